// Round 8
// baseline (415.056 us; speedup 1.0000x reference)
//
#include <hip/hip_runtime.h>
#include <hip/hip_bf16.h>
#include <math.h>

// MimiAttention: B=4, S=2048, HID=512, NH=8, HD=64, SW=250, theta=10000
// Round 8: single fused kernel with SOFTWARE grid barriers (plain launch;
// round 7's hipLaunchCooperativeKernel never executed). 512 blocks x 256 thr,
// 2 blocks/CU guaranteed (VGPR<=256 via launch_bounds, LDS 38.25KB). Barrier:
// agent-scope atomic arrive + sleep-spin, device fences for cross-XCD vis.
// Math identical to round 6 (passed, absmax 0.0156).

#define B_   4
#define S_   2048
#define HID_ 512
#define NH_  8
#define HD_  64
#define SW_  250
#define GRID_ 512

typedef __bf16 bf16x8 __attribute__((ext_vector_type(8)));
typedef __bf16 bf16x4 __attribute__((ext_vector_type(4)));
typedef float f32x4 __attribute__((ext_vector_type(4)));
using bf16_t = __hip_bfloat16;
typedef unsigned int u32;

__device__ __forceinline__ void glds16(const bf16_t* g, bf16_t* l) {
    __builtin_amdgcn_global_load_lds(
        (const __attribute__((address_space(1))) u32*)g,
        (__attribute__((address_space(3))) u32*)l, 16, 0, 0);
}

// software grid barrier: one counter per stage (zeroed host-side each call)
__device__ __forceinline__ void grid_barrier(int* cnt) {
    __syncthreads();
    if (threadIdx.x == 0) {
        __threadfence();                                    // release data
        __hip_atomic_fetch_add(cnt, 1, __ATOMIC_ACQ_REL, __HIP_MEMORY_SCOPE_AGENT);
        while (__hip_atomic_load(cnt, __ATOMIC_ACQUIRE, __HIP_MEMORY_SCOPE_AGENT) < GRID_)
            __builtin_amdgcn_s_sleep(8);
        __threadfence();                                    // acquire data
    }
    __syncthreads();
}

__global__ __launch_bounds__(256, 2) void fused(
    const float* X,  const float* Wq, const float* Wk, const float* Wv,
    const float* Wo,
    bf16_t* Xb, bf16_t* Wcat, bf16_t* Wob, float2* rope,
    bf16_t* Q, bf16_t* K, bf16_t* Vt, bf16_t* A, float* out, int* bar)
{
    __shared__ __align__(16) char smem_raw[39168];  // max over phases
    const int tid = threadIdx.x;
    const int wave = tid >> 6, lane = tid & 63;
    const int quad = lane >> 4, l16 = lane & 15;

    // ================= phase 0: fp32->bf16 convert + rope table ============
    for (int blk = blockIdx.x; blk < 2624; blk += GRID_) {
        if (blk >= 2560) {
            int e0 = ((blk - 2560) * 256 + tid) * 4;
#pragma unroll
            for (int j = 0; j < 4; ++j) {
                int e = e0 + j;
                int s = e >> 5, i = e & 31;
                float inv = exp2f(-(float)i * 0.41524101186f);  // 10000^(-i/32)
                float sn, cs;
                sincosf((float)s * inv, &sn, &cs);
                rope[e] = make_float2(cs, sn);
            }
            continue;
        }
        const float* s; bf16_t* d; size_t base;
        if (blk < 2048)      { s = X;  d = Xb;            base = (size_t)blk * 2048; }
        else if (blk < 2176) { s = Wq; d = Wcat;          base = (size_t)(blk - 2048) * 2048; }
        else if (blk < 2304) { s = Wk; d = Wcat + 262144; base = (size_t)(blk - 2176) * 2048; }
        else if (blk < 2432) { s = Wv; d = Wcat + 524288; base = (size_t)(blk - 2304) * 2048; }
        else                 { s = Wo; d = Wob;           base = (size_t)(blk - 2432) * 2048; }
        size_t i = base + (size_t)tid * 8;
        float4 a = *reinterpret_cast<const float4*>(s + i);
        float4 b = *reinterpret_cast<const float4*>(s + i + 4);
        bf16x8 r;
        r[0] = (__bf16)a.x; r[1] = (__bf16)a.y; r[2] = (__bf16)a.z; r[3] = (__bf16)a.w;
        r[4] = (__bf16)b.x; r[5] = (__bf16)b.y; r[6] = (__bf16)b.z; r[7] = (__bf16)b.w;
        *reinterpret_cast<bf16x8*>(d + i) = r;
    }
    grid_barrier(bar + 0);

    // ================= phase 1: QKV GEMM + RoPE + Vt =======================
    {
        bf16_t* As = (bf16_t*)smem_raw;        // 128*32
        bf16_t* Bs = As + 4096;                // 128*32
        const int wm = wave & 1, wn = wave >> 1;
        for (int t = blockIdx.x; t < 768; t += GRID_) {
            __syncthreads();                   // protect LDS reuse across tiles
            const int m0 = (t & 63) * 128, n0 = (t >> 6) * 128;
            f32x4 acc[4][4] = {};
            for (int k0 = 0; k0 < HID_; k0 += 32) {
#pragma unroll
                for (int tt = 0; tt < 2; ++tt) {
                    int flat = tt * 2048 + tid * 8;
                    int row = flat >> 5, col = flat & 31;
                    glds16(Xb + (size_t)(m0 + row) * HID_ + k0 + col, As + flat);
                    glds16(Wcat + (size_t)(n0 + row) * HID_ + k0 + col, Bs + flat);
                }
                __syncthreads();
                bf16x8 af[4], bfr[4];
#pragma unroll
                for (int i = 0; i < 4; ++i) {
                    af[i]  = *reinterpret_cast<const bf16x8*>(&As[(wm * 64 + i * 16 + l16) * 32 + quad * 8]);
                    bfr[i] = *reinterpret_cast<const bf16x8*>(&Bs[(wn * 64 + i * 16 + l16) * 32 + quad * 8]);
                }
#pragma unroll
                for (int mi = 0; mi < 4; ++mi)
#pragma unroll
                    for (int ni = 0; ni < 4; ++ni)
                        acc[mi][ni] = __builtin_amdgcn_mfma_f32_16x16x32_bf16(af[mi], bfr[ni], acc[mi][ni], 0, 0, 0);
                __syncthreads();
            }
            // epilogue via wave-private LDS tile (64x68)
            const int seg = n0 >> 9;
            const int hh  = ((n0 & 511) + wn * 64) >> 6;
            bf16_t* wt = (bf16_t*)smem_raw + wave * 4352;
            const int mbase = m0 + wm * 64;
            const int bb = mbase >> 11;
            const int sbase = mbase & (S_ - 1);

            if (seg < 2) {
                const float qs = (seg == 0) ? 0.125f : 1.0f;
#pragma unroll
                for (int mi = 0; mi < 4; ++mi)
#pragma unroll
                    for (int r = 0; r < 4; ++r) {
                        int lrow = mi * 16 + quad * 4 + r;
                        int s = sbase + lrow;
#pragma unroll
                        for (int ip = 0; ip < 2; ++ip) {
                            float2 t2 = rope[(size_t)s * 32 + ip * 16 + l16];
                            float x1 = acc[mi][ip][r], x2 = acc[mi][ip + 2][r];
                            wt[lrow * 68 + ip * 16 + l16]      = __float2bfloat16((x1 * t2.x - x2 * t2.y) * qs);
                            wt[lrow * 68 + ip * 16 + l16 + 32] = __float2bfloat16((x2 * t2.x + x1 * t2.y) * qs);
                        }
                    }
                bf16_t* Y = (seg == 0) ? Q : K;
#pragma unroll
                for (int it = 0; it < 8; ++it) {
                    int e = it * 64 + lane;
                    int sr = e >> 3, doff = (e & 7) * 8;
                    size_t g = ((size_t)(bb * NH_ + hh) * S_ + sbase + sr) * HD_ + doff;
                    *reinterpret_cast<bf16x8*>(Y + g) =
                        *reinterpret_cast<const bf16x8*>(wt + sr * 68 + doff);
                }
            } else {
#pragma unroll
                for (int mi = 0; mi < 4; ++mi)
#pragma unroll
                    for (int ni = 0; ni < 4; ++ni)
#pragma unroll
                        for (int r = 0; r < 4; ++r)
                            wt[(ni * 16 + l16) * 68 + mi * 16 + quad * 4 + r] =
                                __float2bfloat16(acc[mi][ni][r]);
#pragma unroll
                for (int it = 0; it < 8; ++it) {
                    int e = it * 64 + lane;
                    int d = e >> 3, soff = (e & 7) * 8;
                    size_t g = ((size_t)(bb * NH_ + hh) * HD_ + d) * S_ + sbase + soff;
                    *reinterpret_cast<bf16x8*>(Vt + g) =
                        *reinterpret_cast<const bf16x8*>(wt + d * 68 + soff);
                }
            }
        }
    }
    grid_barrier(bar + 1);

    // ================= phase 2: one-pass windowed attention ================
    {
        __bf16* pt = (__bf16*)smem_raw;                 // [4][16][296]
        float* sums_l = (float*)(smem_raw + 37888);     // [4][16]
        for (int v = blockIdx.x; v < 1024; v += GRID_) {
            const int h = (v >> 5) & 7, b = v >> 8;
            const int q0 = ((v & 31) * 4 + wave) * 16;
            const size_t bh  = (size_t)(b * NH_ + h) * S_;
            const size_t bhd = (size_t)(b * NH_ + h) * HD_;

            bf16x8 qf0, qf1;
            {
                const bf16_t* qp = Q + (bh + q0 + l16) * HD_ + quad * 8;
                qf0 = *reinterpret_cast<const bf16x8*>(qp);
                qf1 = *reinterpret_cast<const bf16x8*>(qp + 32);
            }
            const int kstart = (q0 > SW_) ? ((q0 - SW_) & ~31) : 0;
            const int nt = (q0 + 15 - kstart + 32) >> 5;   // 1..9
            const int qq = q0 + l16;

            f32x4 s[9][2];
#pragma unroll
            for (int t = 0; t < 9; ++t) {
                if (t < nt) {
                    const int kb = kstart + t * 32;
#pragma unroll
                    for (int half = 0; half < 2; ++half) {
                        const bf16_t* kp = K + (bh + kb + half * 16 + l16) * HD_ + quad * 8;
                        bf16x8 k0 = *reinterpret_cast<const bf16x8*>(kp);
                        bf16x8 k1 = *reinterpret_cast<const bf16x8*>(kp + 32);
                        f32x4 z = {};
                        z = __builtin_amdgcn_mfma_f32_16x16x32_bf16(k0, qf0, z, 0, 0, 0);
                        z = __builtin_amdgcn_mfma_f32_16x16x32_bf16(k1, qf1, z, 0, 0, 0);
                        const int kbase = kb + half * 16 + quad * 4;
#pragma unroll
                        for (int r = 0; r < 4; ++r) {
                            int key = kbase + r;
                            bool keep = (key <= qq) && (qq - key <= SW_);
                            s[t][half][r] = keep ? z[r] : -3.0e38f;
                        }
                    }
                }
            }
            float mx = -3.0e38f;
#pragma unroll
            for (int t = 0; t < 9; ++t)
                if (t < nt)
#pragma unroll
                    for (int half = 0; half < 2; ++half)
#pragma unroll
                        for (int r = 0; r < 4; ++r)
                            mx = fmaxf(mx, s[t][half][r]);
            mx = fmaxf(mx, __shfl_xor(mx, 16, 64));
            mx = fmaxf(mx, __shfl_xor(mx, 32, 64));

            float sum = 0.f;
#pragma unroll
            for (int t = 0; t < 9; ++t)
                if (t < nt)
#pragma unroll
                    for (int half = 0; half < 2; ++half) {
                        bf16x4 pk;
#pragma unroll
                        for (int r = 0; r < 4; ++r) {
                            float p = __expf(s[t][half][r] - mx);
                            sum += p;
                            pk[r] = (__bf16)p;
                        }
                        *reinterpret_cast<bf16x4*>(
                            &pt[(wave * 16 + l16) * 296 + t * 32 + half * 16 + quad * 4]) = pk;
                    }
            sum += __shfl_xor(sum, 16, 64);
            sum += __shfl_xor(sum, 32, 64);
            if (quad == 0) sums_l[wave * 16 + l16] = sum;

            f32x4 o[4] = {};
#pragma unroll
            for (int t = 0; t < 9; ++t) {
                if (t < nt) {
                    const int kb = kstart + t * 32;
                    bf16x8 pf = *reinterpret_cast<const bf16x8*>(
                        &pt[(wave * 16 + l16) * 296 + t * 32 + quad * 8]);
#pragma unroll
                    for (int nf = 0; nf < 4; ++nf) {
                        const bf16_t* vp = Vt + (bhd + nf * 16 + l16) * S_ + kb + quad * 8;
                        bf16x8 vf = *reinterpret_cast<const bf16x8*>(vp);
                        o[nf] = __builtin_amdgcn_mfma_f32_16x16x32_bf16(pf, vf, o[nf], 0, 0, 0);
                    }
                }
            }
            float inv_l[4];
#pragma unroll
            for (int r = 0; r < 4; ++r) inv_l[r] = 1.0f / sums_l[wave * 16 + quad * 4 + r];
#pragma unroll
            for (int nf = 0; nf < 4; ++nf)
#pragma unroll
                for (int r = 0; r < 4; ++r) {
                    int qr = q0 + quad * 4 + r;
                    A[((size_t)(b * S_ + qr)) * HID_ + h * HD_ + nf * 16 + l16] =
                        __float2bfloat16(o[nf][r] * inv_l[r]);
                }
        }
    }
    grid_barrier(bar + 2);

    // ================= phase 3: output projection ==========================
    {
        bf16_t* As = (bf16_t*)smem_raw;    // 128*32
        bf16_t* Bs = As + 4096;            // 64*32
        const int v = blockIdx.x;          // 512 tiles exactly
        const int m0 = (v & 63) * 128, n0 = (v >> 6) * 64;
        f32x4 acc[2][4] = {};
        for (int k0 = 0; k0 < HID_; k0 += 32) {
#pragma unroll
            for (int tt = 0; tt < 2; ++tt) {
                int flat = tt * 2048 + tid * 8;
                int row = flat >> 5, col = flat & 31;
                glds16(A + (size_t)(m0 + row) * HID_ + k0 + col, As + flat);
            }
            {
                int flat = tid * 8;
                int row = flat >> 5, col = flat & 31;
                glds16(Wob + (size_t)(n0 + row) * HID_ + k0 + col, Bs + flat);
            }
            __syncthreads();
            bf16x8 af[2], bfr[4];
#pragma unroll
            for (int i = 0; i < 2; ++i)
                af[i] = *reinterpret_cast<const bf16x8*>(&As[(wave * 32 + i * 16 + l16) * 32 + quad * 8]);
#pragma unroll
            for (int i = 0; i < 4; ++i)
                bfr[i] = *reinterpret_cast<const bf16x8*>(&Bs[(i * 16 + l16) * 32 + quad * 8]);
#pragma unroll
            for (int mi = 0; mi < 2; ++mi)
#pragma unroll
                for (int ni = 0; ni < 4; ++ni)
                    acc[mi][ni] = __builtin_amdgcn_mfma_f32_16x16x32_bf16(af[mi], bfr[ni], acc[mi][ni], 0, 0, 0);
            __syncthreads();
        }
#pragma unroll
        for (int mi = 0; mi < 2; ++mi)
#pragma unroll
            for (int ni = 0; ni < 4; ++ni)
#pragma unroll
                for (int r = 0; r < 4; ++r) {
                    int m = m0 + wave * 32 + mi * 16 + quad * 4 + r;
                    int n = n0 + ni * 16 + l16;
                    out[(size_t)m * HID_ + n] = acc[mi][ni][r];
                }
    }
}

// ---------------------------------------------------------------------------
extern "C" void kernel_launch(void* const* d_in, const int* in_sizes, int n_in,
                              void* d_out, int out_size, void* d_ws, size_t ws_size,
                              hipStream_t stream)
{
    const float* X  = (const float*)d_in[0];
    // d_in[1] = position_ids (broadcast arange(S); pos derived from s index)
    const float* Wq = (const float*)d_in[2];
    const float* Wk = (const float*)d_in[3];
    const float* Wv = (const float*)d_in[4];
    const float* Wo = (const float*)d_in[5];
    float* outp = (float*)d_out;

    char* ws = (char*)d_ws;
    const size_t elems = (size_t)B_ * NH_ * S_ * HD_;   // 4,194,304
    const size_t wsz   = (size_t)HID_ * HID_;           // 262,144
    bf16_t* Q    = (bf16_t*)ws;
    bf16_t* K    = Q + elems;
    bf16_t* Vt   = K + elems;
    bf16_t* Xb   = Vt + elems;
    bf16_t* A    = Xb + elems;
    bf16_t* Wcat = A + elems;
    bf16_t* Wob  = Wcat + 3 * wsz;
    float2* rope = (float2*)(Wob + wsz);   // 2048 x 32 float2 = 512 KB
    int*    bar  = (int*)(rope + 65536);   // 3 stage counters

    hipMemsetAsync(bar, 0, 3 * sizeof(int), stream);
    fused<<<GRID_, 256, 0, stream>>>(X, Wq, Wk, Wv, Wo,
                                     Xb, Wcat, Wob, rope,
                                     Q, K, Vt, A, outp, bar);
}

// Round 9
// 305.628 us; speedup vs baseline: 1.3580x; 1.3580x over previous
//
#include <hip/hip_runtime.h>
#include <hip/hip_bf16.h>
#include <math.h>

// MimiAttention: B=4, S=2048, HID=512, NH=8, HD=64, SW=250, theta=10000
// Round 9: back to multi-launch (round 8 proved software grid barriers cost
// ~90us each on MI355X). cvt kernel ELIMINATED: GEMMs stage fp32 operands
// directly to LDS (glds16 = 4 floats/lane) and convert to bf16 at frag-read;
// RoPE computed in-epilogue with __sincosf. 3 kernels total.

#define B_   4
#define S_   2048
#define HID_ 512
#define NH_  8
#define HD_  64
#define SW_  250

typedef __bf16 bf16x8 __attribute__((ext_vector_type(8)));
typedef __bf16 bf16x4 __attribute__((ext_vector_type(4)));
typedef float f32x4 __attribute__((ext_vector_type(4)));
using bf16_t = __hip_bfloat16;
typedef unsigned int u32;

// async global->LDS, 16 B per lane (wave-uniform base + lane*16 semantics)
__device__ __forceinline__ void glds16(const void* g, void* l) {
    __builtin_amdgcn_global_load_lds(
        (const __attribute__((address_space(1))) u32*)g,
        (__attribute__((address_space(3))) u32*)l, 16, 0, 0);
}

// read 8 consecutive fp32 from LDS, convert to bf16x8 (A/B frag build)
__device__ __forceinline__ bf16x8 frag_cvt(const float* p) {
    float4 a = *reinterpret_cast<const float4*>(p);
    float4 b = *reinterpret_cast<const float4*>(p + 4);
    bf16x8 r;
    r[0] = (__bf16)a.x; r[1] = (__bf16)a.y; r[2] = (__bf16)a.z; r[3] = (__bf16)a.w;
    r[4] = (__bf16)b.x; r[5] = (__bf16)b.y; r[6] = (__bf16)b.z; r[7] = (__bf16)b.w;
    return r;
}

// ---------------------------------------------------------------------------
// Fused QKV GEMM, fp32 inputs staged directly. C[8192x1536] = X @ [Wq;Wk;Wv]^T
// 128x128 tile, BK=32, 4 waves 2x2. Epilogue: RoPE (__sincosf) for Q/K,
// V stored transposed; all stores 128B-coalesced via wave-private LDS tile.
// MFMA layouts (m89/m91): A[m=l16][k=quad*8+j], B^T[n=l16][k=quad*8+j],
// C/D col=l16, row=quad*4+r.
// ---------------------------------------------------------------------------
__global__ __launch_bounds__(256) void qkv_gemm(
    const float* __restrict__ X,
    const float* __restrict__ Wq, const float* __restrict__ Wk,
    const float* __restrict__ Wv,
    bf16_t* __restrict__ Q, bf16_t* __restrict__ Kbuf, bf16_t* __restrict__ Vt)
{
    __shared__ __align__(16) char smem_raw[34816];  // max(32KB stage, 34KB epi)
    float* As = (float*)smem_raw;          // 128*32 fp32 = 16 KB
    float* Bs = As + 4096;                 // 128*32 fp32 = 16 KB
    const int tid = threadIdx.x;
    const int wave = tid >> 6, lane = tid & 63;
    const int quad = lane >> 4, l16 = lane & 15;
    const int wm = wave & 1, wn = wave >> 1;
    const int m0 = blockIdx.x * 128, n0 = blockIdx.y * 128;

    const int seg = n0 >> 9;               // 0=Q 1=K 2=V
    const float* W = (seg == 0) ? Wq : (seg == 1) ? Wk : Wv;
    const int nrow0 = n0 & 511;            // row base within selected W

    f32x4 acc[4][4] = {};
    for (int k0 = 0; k0 < HID_; k0 += 32) {
        // stage A (X) and B (W) fp32 tiles: 4096 floats each, 4 rounds of 1024
#pragma unroll
        for (int rr = 0; rr < 4; ++rr) {
            int flat = rr * 1024 + tid * 4;        // float units, 16 B/lane
            int row = flat >> 5, col = flat & 31;
            glds16(X + (size_t)(m0 + row) * HID_ + k0 + col, As + flat);
            glds16(W + (size_t)(nrow0 + row) * HID_ + k0 + col, Bs + flat);
        }
        __syncthreads();
        bf16x8 af[4], bfr[4];
#pragma unroll
        for (int i = 0; i < 4; ++i) {
            af[i]  = frag_cvt(&As[(wm * 64 + i * 16 + l16) * 32 + quad * 8]);
            bfr[i] = frag_cvt(&Bs[(wn * 64 + i * 16 + l16) * 32 + quad * 8]);
        }
#pragma unroll
        for (int mi = 0; mi < 4; ++mi)
#pragma unroll
            for (int ni = 0; ni < 4; ++ni)
                acc[mi][ni] = __builtin_amdgcn_mfma_f32_16x16x32_bf16(af[mi], bfr[ni], acc[mi][ni], 0, 0, 0);
        __syncthreads();
    }

    // ---- epilogue via wave-private 64x68 bf16 LDS tile ----
    const int hh = ((n0 & 511) + wn * 64) >> 6;   // head of this wave
    bf16_t* wt = (bf16_t*)smem_raw + wave * 4352;
    const int mbase = m0 + wm * 64;
    const int bb = mbase >> 11;
    const int sbase = mbase & (S_ - 1);           // 64-row tile never crosses batch

    if (seg < 2) {
        const float qs = (seg == 0) ? 0.125f : 1.0f;
        const float c = 0.41524101186f;           // log2(10000)/32
        float inv0 = exp2f(-(float)l16 * c);
        float inv1 = exp2f(-(float)(l16 + 16) * c);
#pragma unroll
        for (int mi = 0; mi < 4; ++mi)
#pragma unroll
            for (int r = 0; r < 4; ++r) {
                int lrow = mi * 16 + quad * 4 + r;
                float sf = (float)(sbase + lrow);
#pragma unroll
                for (int ip = 0; ip < 2; ++ip) {
                    float sn, cs_;
                    __sincosf(sf * (ip ? inv1 : inv0), &sn, &cs_);
                    float x1 = acc[mi][ip][r], x2 = acc[mi][ip + 2][r];
                    wt[lrow * 68 + ip * 16 + l16]      = __float2bfloat16((x1 * cs_ - x2 * sn) * qs);
                    wt[lrow * 68 + ip * 16 + l16 + 32] = __float2bfloat16((x2 * cs_ + x1 * sn) * qs);
                }
            }
        bf16_t* Y = (seg == 0) ? Q : Kbuf;
#pragma unroll
        for (int it = 0; it < 8; ++it) {
            int e = it * 64 + lane;
            int sr = e >> 3, doff = (e & 7) * 8;
            size_t g = ((size_t)(bb * NH_ + hh) * S_ + sbase + sr) * HD_ + doff;
            *reinterpret_cast<bf16x8*>(Y + g) =
                *reinterpret_cast<const bf16x8*>(wt + sr * 68 + doff);
        }
    } else {
        // V: deposit transposed (rows = d, cols = s-local), store along s
#pragma unroll
        for (int mi = 0; mi < 4; ++mi)
#pragma unroll
            for (int ni = 0; ni < 4; ++ni)
#pragma unroll
                for (int r = 0; r < 4; ++r)
                    wt[(ni * 16 + l16) * 68 + mi * 16 + quad * 4 + r] =
                        __float2bfloat16(acc[mi][ni][r]);
#pragma unroll
        for (int it = 0; it < 8; ++it) {
            int e = it * 64 + lane;
            int d = e >> 3, soff = (e & 7) * 8;
            size_t g = ((size_t)(bb * NH_ + hh) * HD_ + d) * S_ + sbase + soff;
            *reinterpret_cast<bf16x8*>(Vt + g) =
                *reinterpret_cast<const bf16x8*>(wt + d * 68 + soff);
        }
    }
}

// ---------------------------------------------------------------------------
// One-pass full-window attention (unchanged from round 6, which passed).
// One wave = 16 queries; <=9 key-tiles of 32 all in VGPRs; S^T trick
// (K*Q^T) -> scalar softmax state, 2-step butterflies, b64 P deposit.
// ---------------------------------------------------------------------------
__global__ __launch_bounds__(256) void attn_mfma(
    const bf16_t* __restrict__ Q, const bf16_t* __restrict__ K,
    const bf16_t* __restrict__ Vt, bf16_t* __restrict__ A)
{
    __shared__ __align__(16) __bf16 pt[4][16][296];
    __shared__ float sums_l[4][16];
    const int wave = threadIdx.x >> 6, lane = threadIdx.x & 63;
    const int quad = lane >> 4, l16 = lane & 15;
    const int h = blockIdx.y, b = blockIdx.z;
    const int q0 = (blockIdx.x * 4 + wave) * 16;
    const size_t bh  = (size_t)(b * NH_ + h) * S_;
    const size_t bhd = (size_t)(b * NH_ + h) * HD_;

    bf16x8 qf0, qf1;
    {
        const bf16_t* qp = Q + (bh + q0 + l16) * HD_ + quad * 8;
        qf0 = *reinterpret_cast<const bf16x8*>(qp);
        qf1 = *reinterpret_cast<const bf16x8*>(qp + 32);
    }
    const int kstart = (q0 > SW_) ? ((q0 - SW_) & ~31) : 0;
    const int nt = (q0 + 15 - kstart + 32) >> 5;   // 1..9, wave-uniform
    const int qq = q0 + l16;

    f32x4 s[9][2];
#pragma unroll
    for (int t = 0; t < 9; ++t) {
        if (t < nt) {
            const int kb = kstart + t * 32;
#pragma unroll
            for (int half = 0; half < 2; ++half) {
                const bf16_t* kp = K + (bh + kb + half * 16 + l16) * HD_ + quad * 8;
                bf16x8 k0 = *reinterpret_cast<const bf16x8*>(kp);
                bf16x8 k1 = *reinterpret_cast<const bf16x8*>(kp + 32);
                f32x4 z = {};
                z = __builtin_amdgcn_mfma_f32_16x16x32_bf16(k0, qf0, z, 0, 0, 0);
                z = __builtin_amdgcn_mfma_f32_16x16x32_bf16(k1, qf1, z, 0, 0, 0);
                const int kbase = kb + half * 16 + quad * 4;
#pragma unroll
                for (int r = 0; r < 4; ++r) {
                    int key = kbase + r;
                    bool keep = (key <= qq) && (qq - key <= SW_);
                    s[t][half][r] = keep ? z[r] : -3.0e38f;
                }
            }
        }
    }
    float mx = -3.0e38f;
#pragma unroll
    for (int t = 0; t < 9; ++t)
        if (t < nt)
#pragma unroll
            for (int half = 0; half < 2; ++half)
#pragma unroll
                for (int r = 0; r < 4; ++r)
                    mx = fmaxf(mx, s[t][half][r]);
    mx = fmaxf(mx, __shfl_xor(mx, 16, 64));
    mx = fmaxf(mx, __shfl_xor(mx, 32, 64));

    float sum = 0.f;
#pragma unroll
    for (int t = 0; t < 9; ++t)
        if (t < nt)
#pragma unroll
            for (int half = 0; half < 2; ++half) {
                bf16x4 pk;
#pragma unroll
                for (int r = 0; r < 4; ++r) {
                    float p = __expf(s[t][half][r] - mx);
                    sum += p;
                    pk[r] = (__bf16)p;
                }
                *reinterpret_cast<bf16x4*>(&pt[wave][l16][t * 32 + half * 16 + quad * 4]) = pk;
            }
    sum += __shfl_xor(sum, 16, 64);
    sum += __shfl_xor(sum, 32, 64);
    if (quad == 0) sums_l[wave][l16] = sum;   // wave-local, no barrier

    f32x4 o[4] = {};
#pragma unroll
    for (int t = 0; t < 9; ++t) {
        if (t < nt) {
            const int kb = kstart + t * 32;
            bf16x8 pf = *reinterpret_cast<const bf16x8*>(&pt[wave][l16][t * 32 + quad * 8]);
#pragma unroll
            for (int nf = 0; nf < 4; ++nf) {
                const bf16_t* vp = Vt + (bhd + nf * 16 + l16) * S_ + kb + quad * 8;
                bf16x8 vf = *reinterpret_cast<const bf16x8*>(vp);
                o[nf] = __builtin_amdgcn_mfma_f32_16x16x32_bf16(pf, vf, o[nf], 0, 0, 0);
            }
        }
    }
    float inv_l[4];
#pragma unroll
    for (int r = 0; r < 4; ++r) inv_l[r] = 1.0f / sums_l[wave][quad * 4 + r];
#pragma unroll
    for (int nf = 0; nf < 4; ++nf)
#pragma unroll
        for (int r = 0; r < 4; ++r) {
            int qr = q0 + quad * 4 + r;
            A[((size_t)(b * S_ + qr)) * HID_ + h * HD_ + nf * 16 + l16] =
                __float2bfloat16(o[nf][r] * inv_l[r]);
        }
}

// ---------------------------------------------------------------------------
// Output projection: out[8192x512] = A(bf16) @ Wo(fp32)^T, 128x64 tile, BK=32.
// A staged as bf16 (glds16), Wo staged fp32 and converted at frag-read.
// ---------------------------------------------------------------------------
__global__ __launch_bounds__(256) void out_proj(
    const bf16_t* __restrict__ Ain, const float* __restrict__ Wo,
    float* __restrict__ out)
{
    __shared__ __align__(16) bf16_t As[128 * 32];  // 8 KB
    __shared__ __align__(16) float  Bs[64 * 32];   // 8 KB
    const int tid = threadIdx.x;
    const int wave = tid >> 6, lane = tid & 63;
    const int quad = lane >> 4, l16 = lane & 15;
    const int m0 = blockIdx.x * 128, n0 = blockIdx.y * 64;

    f32x4 acc[2][4] = {};
    for (int k0 = 0; k0 < HID_; k0 += 32) {
#pragma unroll
        for (int tt = 0; tt < 2; ++tt) {
            int flat = tt * 2048 + tid * 8;        // bf16 units
            int row = flat >> 5, col = flat & 31;
            glds16(Ain + (size_t)(m0 + row) * HID_ + k0 + col, As + flat);
        }
#pragma unroll
        for (int rr = 0; rr < 2; ++rr) {
            int flat = rr * 1024 + tid * 4;        // float units
            int row = flat >> 5, col = flat & 31;
            glds16(Wo + (size_t)(n0 + row) * HID_ + k0 + col, Bs + flat);
        }
        __syncthreads();
        bf16x8 af[2], bfr[4];
#pragma unroll
        for (int i = 0; i < 2; ++i)
            af[i] = *reinterpret_cast<const bf16x8*>(&As[(wave * 32 + i * 16 + l16) * 32 + quad * 8]);
#pragma unroll
        for (int i = 0; i < 4; ++i)
            bfr[i] = frag_cvt(&Bs[(i * 16 + l16) * 32 + quad * 8]);
#pragma unroll
        for (int mi = 0; mi < 2; ++mi)
#pragma unroll
            for (int ni = 0; ni < 4; ++ni)
                acc[mi][ni] = __builtin_amdgcn_mfma_f32_16x16x32_bf16(af[mi], bfr[ni], acc[mi][ni], 0, 0, 0);
        __syncthreads();
    }
#pragma unroll
    for (int mi = 0; mi < 2; ++mi)
#pragma unroll
        for (int ni = 0; ni < 4; ++ni)
#pragma unroll
            for (int r = 0; r < 4; ++r) {
                int m = m0 + wave * 32 + mi * 16 + quad * 4 + r;
                int n = n0 + ni * 16 + l16;
                out[(size_t)m * HID_ + n] = acc[mi][ni][r];
            }
}

// ---------------------------------------------------------------------------
extern "C" void kernel_launch(void* const* d_in, const int* in_sizes, int n_in,
                              void* d_out, int out_size, void* d_ws, size_t ws_size,
                              hipStream_t stream)
{
    const float* X  = (const float*)d_in[0];
    // d_in[1] = position_ids (broadcast arange(S); pos derived from s index)
    const float* Wq = (const float*)d_in[2];
    const float* Wk = (const float*)d_in[3];
    const float* Wv = (const float*)d_in[4];
    const float* Wo = (const float*)d_in[5];

    char* ws = (char*)d_ws;
    const size_t elems = (size_t)B_ * NH_ * S_ * HD_;   // 4,194,304
    bf16_t* Q  = (bf16_t*)ws;
    bf16_t* K  = Q + elems;
    bf16_t* Vt = K + elems;
    bf16_t* A  = Vt + elems;   // total 33.5 MB

    qkv_gemm<<<dim3(64, 12), 256, 0, stream>>>(X, Wq, Wk, Wv, Q, K, Vt);
    attn_mfma<<<dim3(32, 8, 4), 256, 0, stream>>>(Q, K, Vt, A);
    out_proj<<<dim3(64, 8), 256, 0, stream>>>(A, Wo, (float*)d_out);
}

// Round 10
// 154.221 us; speedup vs baseline: 2.6913x; 1.9817x over previous
//
#include <hip/hip_runtime.h>
#include <hip/hip_bf16.h>
#include <math.h>

// MimiAttention: B=4, S=2048, HID=512, NH=8, HD=64, SW=250, theta=10000
// Round 10: round-9 structure (3 kernels, fp32 staged directly, no cvt) +
// XOR quartet swizzle on LDS tiles to kill the 16-way bank conflicts that
// rocprof exposed (SQ_LDS_BANK_CONFLICT 6.8e7 -> ~111us of the 150us qkv).
// glds16 dest must be contiguous, so the swizzle permutes the GLOBAL source
// quartet per 16B slot; reads invert the permutation per logical quartet.

#define B_   4
#define S_   2048
#define HID_ 512
#define NH_  8
#define HD_  64
#define SW_  250

typedef __bf16 bf16x8 __attribute__((ext_vector_type(8)));
typedef __bf16 bf16x4 __attribute__((ext_vector_type(4)));
typedef float f32x4 __attribute__((ext_vector_type(4)));
using bf16_t = __hip_bfloat16;
typedef unsigned int u32;

// async global->LDS, 16 B per lane (wave-uniform base + lane*16 semantics)
__device__ __forceinline__ void glds16(const void* g, void* l) {
    __builtin_amdgcn_global_load_lds(
        (const __attribute__((address_space(1))) u32*)g,
        (__attribute__((address_space(3))) u32*)l, 16, 0, 0);
}

// Swizzled fp32 frag read: logical quartets (quad*2, quad*2+1) of `row`,
// physical quartet = logical ^ (row & 7). 8 bank-groups across 16 lanes.
__device__ __forceinline__ bf16x8 frag_cvt_sw(const float* rowp, int r7, int quad) {
    float4 a = *reinterpret_cast<const float4*>(rowp + (((quad * 2)     ^ r7) << 2));
    float4 b = *reinterpret_cast<const float4*>(rowp + (((quad * 2 + 1) ^ r7) << 2));
    bf16x8 r;
    r[0] = (__bf16)a.x; r[1] = (__bf16)a.y; r[2] = (__bf16)a.z; r[3] = (__bf16)a.w;
    r[4] = (__bf16)b.x; r[5] = (__bf16)b.y; r[6] = (__bf16)b.z; r[7] = (__bf16)b.w;
    return r;
}

// ---------------------------------------------------------------------------
// Fused QKV GEMM, fp32 inputs staged directly (swizzled). C = X @ [Wq;Wk;Wv]^T
// 128x128 tile, BK=32, 4 waves 2x2. Epilogue: RoPE (__sincosf) for Q/K,
// V stored transposed; stores 128B-coalesced via wave-private LDS tile.
// MFMA layouts (m89/m91): A[m=l16][k=quad*8+j], B^T[n=l16][k=quad*8+j],
// C/D col=l16, row=quad*4+r.
// ---------------------------------------------------------------------------
__global__ __launch_bounds__(256) void qkv_gemm(
    const float* __restrict__ X,
    const float* __restrict__ Wq, const float* __restrict__ Wk,
    const float* __restrict__ Wv,
    bf16_t* __restrict__ Q, bf16_t* __restrict__ Kbuf, bf16_t* __restrict__ Vt)
{
    __shared__ __align__(16) char smem_raw[34816];  // max(32KB stage, 34KB epi)
    float* As = (float*)smem_raw;          // 128*32 fp32 = 16 KB
    float* Bs = As + 4096;                 // 128*32 fp32 = 16 KB
    const int tid = threadIdx.x;
    const int wave = tid >> 6, lane = tid & 63;
    const int quad = lane >> 4, l16 = lane & 15;
    const int wm = wave & 1, wn = wave >> 1;
    const int m0 = blockIdx.x * 128, n0 = blockIdx.y * 128;

    const int seg = n0 >> 9;               // 0=Q 1=K 2=V
    const float* W = (seg == 0) ? Wq : (seg == 1) ? Wk : Wv;
    const int nrow0 = n0 & 511;            // row base within selected W

    f32x4 acc[4][4] = {};
    for (int k0 = 0; k0 < HID_; k0 += 32) {
        // stage A (X) and B (W): 4096 floats each, 4 rounds, swizzled source
#pragma unroll
        for (int rr = 0; rr < 4; ++rr) {
            int flat = rr * 1024 + tid * 4;        // float units, 16 B/lane
            int row = flat >> 5;
            int j = (((tid & 7) ^ (row & 7)) << 2); // logical col of this slot
            glds16(X + (size_t)(m0 + row) * HID_ + k0 + j, As + flat);
            glds16(W + (size_t)(nrow0 + row) * HID_ + k0 + j, Bs + flat);
        }
        __syncthreads();
        bf16x8 af[4], bfr[4];
#pragma unroll
        for (int i = 0; i < 4; ++i) {
            int ra = wm * 64 + i * 16 + l16;
            int rb = wn * 64 + i * 16 + l16;
            af[i]  = frag_cvt_sw(As + ra * 32, ra & 7, quad);
            bfr[i] = frag_cvt_sw(Bs + rb * 32, rb & 7, quad);
        }
#pragma unroll
        for (int mi = 0; mi < 4; ++mi)
#pragma unroll
            for (int ni = 0; ni < 4; ++ni)
                acc[mi][ni] = __builtin_amdgcn_mfma_f32_16x16x32_bf16(af[mi], bfr[ni], acc[mi][ni], 0, 0, 0);
        __syncthreads();
    }

    // ---- epilogue via wave-private 64x68 bf16 LDS tile ----
    const int hh = ((n0 & 511) + wn * 64) >> 6;   // head of this wave
    bf16_t* wt = (bf16_t*)smem_raw + wave * 4352;
    const int mbase = m0 + wm * 64;
    const int bb = mbase >> 11;
    const int sbase = mbase & (S_ - 1);           // 64-row tile never crosses batch

    if (seg < 2) {
        const float qs = (seg == 0) ? 0.125f : 1.0f;
        const float c = 0.41524101186f;           // log2(10000)/32
        float inv0 = exp2f(-(float)l16 * c);
        float inv1 = exp2f(-(float)(l16 + 16) * c);
#pragma unroll
        for (int mi = 0; mi < 4; ++mi)
#pragma unroll
            for (int r = 0; r < 4; ++r) {
                int lrow = mi * 16 + quad * 4 + r;
                float sf = (float)(sbase + lrow);
#pragma unroll
                for (int ip = 0; ip < 2; ++ip) {
                    float sn, cs_;
                    __sincosf(sf * (ip ? inv1 : inv0), &sn, &cs_);
                    float x1 = acc[mi][ip][r], x2 = acc[mi][ip + 2][r];
                    wt[lrow * 68 + ip * 16 + l16]      = __float2bfloat16((x1 * cs_ - x2 * sn) * qs);
                    wt[lrow * 68 + ip * 16 + l16 + 32] = __float2bfloat16((x2 * cs_ + x1 * sn) * qs);
                }
            }
        bf16_t* Y = (seg == 0) ? Q : Kbuf;
#pragma unroll
        for (int it = 0; it < 8; ++it) {
            int e = it * 64 + lane;
            int sr = e >> 3, doff = (e & 7) * 8;
            size_t g = ((size_t)(bb * NH_ + hh) * S_ + sbase + sr) * HD_ + doff;
            *reinterpret_cast<bf16x8*>(Y + g) =
                *reinterpret_cast<const bf16x8*>(wt + sr * 68 + doff);
        }
    } else {
        // V: deposit transposed (rows = d, cols = s-local), store along s
#pragma unroll
        for (int mi = 0; mi < 4; ++mi)
#pragma unroll
            for (int ni = 0; ni < 4; ++ni)
#pragma unroll
                for (int r = 0; r < 4; ++r)
                    wt[(ni * 16 + l16) * 68 + mi * 16 + quad * 4 + r] =
                        __float2bfloat16(acc[mi][ni][r]);
#pragma unroll
        for (int it = 0; it < 8; ++it) {
            int e = it * 64 + lane;
            int d = e >> 3, soff = (e & 7) * 8;
            size_t g = ((size_t)(bb * NH_ + hh) * HD_ + d) * S_ + sbase + soff;
            *reinterpret_cast<bf16x8*>(Vt + g) =
                *reinterpret_cast<const bf16x8*>(wt + d * 68 + soff);
        }
    }
}

// ---------------------------------------------------------------------------
// One-pass full-window attention (unchanged; passed rounds 6/8/9).
// ---------------------------------------------------------------------------
__global__ __launch_bounds__(256) void attn_mfma(
    const bf16_t* __restrict__ Q, const bf16_t* __restrict__ K,
    const bf16_t* __restrict__ Vt, bf16_t* __restrict__ A)
{
    __shared__ __align__(16) __bf16 pt[4][16][296];
    __shared__ float sums_l[4][16];
    const int wave = threadIdx.x >> 6, lane = threadIdx.x & 63;
    const int quad = lane >> 4, l16 = lane & 15;
    const int h = blockIdx.y, b = blockIdx.z;
    const int q0 = (blockIdx.x * 4 + wave) * 16;
    const size_t bh  = (size_t)(b * NH_ + h) * S_;
    const size_t bhd = (size_t)(b * NH_ + h) * HD_;

    bf16x8 qf0, qf1;
    {
        const bf16_t* qp = Q + (bh + q0 + l16) * HD_ + quad * 8;
        qf0 = *reinterpret_cast<const bf16x8*>(qp);
        qf1 = *reinterpret_cast<const bf16x8*>(qp + 32);
    }
    const int kstart = (q0 > SW_) ? ((q0 - SW_) & ~31) : 0;
    const int nt = (q0 + 15 - kstart + 32) >> 5;   // 1..9, wave-uniform
    const int qq = q0 + l16;

    f32x4 s[9][2];
#pragma unroll
    for (int t = 0; t < 9; ++t) {
        if (t < nt) {
            const int kb = kstart + t * 32;
#pragma unroll
            for (int half = 0; half < 2; ++half) {
                const bf16_t* kp = K + (bh + kb + half * 16 + l16) * HD_ + quad * 8;
                bf16x8 k0 = *reinterpret_cast<const bf16x8*>(kp);
                bf16x8 k1 = *reinterpret_cast<const bf16x8*>(kp + 32);
                f32x4 z = {};
                z = __builtin_amdgcn_mfma_f32_16x16x32_bf16(k0, qf0, z, 0, 0, 0);
                z = __builtin_amdgcn_mfma_f32_16x16x32_bf16(k1, qf1, z, 0, 0, 0);
                const int kbase = kb + half * 16 + quad * 4;
#pragma unroll
                for (int r = 0; r < 4; ++r) {
                    int key = kbase + r;
                    bool keep = (key <= qq) && (qq - key <= SW_);
                    s[t][half][r] = keep ? z[r] : -3.0e38f;
                }
            }
        }
    }
    float mx = -3.0e38f;
#pragma unroll
    for (int t = 0; t < 9; ++t)
        if (t < nt)
#pragma unroll
            for (int half = 0; half < 2; ++half)
#pragma unroll
                for (int r = 0; r < 4; ++r)
                    mx = fmaxf(mx, s[t][half][r]);
    mx = fmaxf(mx, __shfl_xor(mx, 16, 64));
    mx = fmaxf(mx, __shfl_xor(mx, 32, 64));

    float sum = 0.f;
#pragma unroll
    for (int t = 0; t < 9; ++t)
        if (t < nt)
#pragma unroll
            for (int half = 0; half < 2; ++half) {
                bf16x4 pk;
#pragma unroll
                for (int r = 0; r < 4; ++r) {
                    float p = __expf(s[t][half][r] - mx);
                    sum += p;
                    pk[r] = (__bf16)p;
                }
                *reinterpret_cast<bf16x4*>(&pt[wave][l16][t * 32 + half * 16 + quad * 4]) = pk;
            }
    sum += __shfl_xor(sum, 16, 64);
    sum += __shfl_xor(sum, 32, 64);
    if (quad == 0) sums_l[wave][l16] = sum;   // wave-local, no barrier

    f32x4 o[4] = {};
#pragma unroll
    for (int t = 0; t < 9; ++t) {
        if (t < nt) {
            const int kb = kstart + t * 32;
            bf16x8 pf = *reinterpret_cast<const bf16x8*>(&pt[wave][l16][t * 32 + quad * 8]);
#pragma unroll
            for (int nf = 0; nf < 4; ++nf) {
                const bf16_t* vp = Vt + (bhd + nf * 16 + l16) * S_ + kb + quad * 8;
                bf16x8 vf = *reinterpret_cast<const bf16x8*>(vp);
                o[nf] = __builtin_amdgcn_mfma_f32_16x16x32_bf16(pf, vf, o[nf], 0, 0, 0);
            }
        }
    }
    float inv_l[4];
#pragma unroll
    for (int r = 0; r < 4; ++r) inv_l[r] = 1.0f / sums_l[wave][quad * 4 + r];
#pragma unroll
    for (int nf = 0; nf < 4; ++nf)
#pragma unroll
        for (int r = 0; r < 4; ++r) {
            int qr = q0 + quad * 4 + r;
            A[((size_t)(b * S_ + qr)) * HID_ + h * HD_ + nf * 16 + l16] =
                __float2bfloat16(o[nf][r] * inv_l[r]);
        }
}

// ---------------------------------------------------------------------------
// Output projection: out[8192x512] = A(bf16) @ Wo(fp32)^T, 128x64 tile, BK=32.
// A bf16 tile swizzled with mask (row>>1)&3; Wo fp32 tile swizzled (row&7).
// ---------------------------------------------------------------------------
__global__ __launch_bounds__(256) void out_proj(
    const bf16_t* __restrict__ Ain, const float* __restrict__ Wo,
    float* __restrict__ out)
{
    __shared__ __align__(16) bf16_t As[128 * 32];  // 8 KB
    __shared__ __align__(16) float  Bs[64 * 32];   // 8 KB
    const int tid = threadIdx.x;
    const int wave = tid >> 6, lane = tid & 63;
    const int quad = lane >> 4, l16 = lane & 15;
    const int m0 = blockIdx.x * 128, n0 = blockIdx.y * 64;

    f32x4 acc[2][4] = {};
    for (int k0 = 0; k0 < HID_; k0 += 32) {
#pragma unroll
        for (int tt = 0; tt < 2; ++tt) {
            int flat = tt * 2048 + tid * 8;        // bf16 units
            int row = flat >> 5;
            int j = (((tid & 3) ^ ((row >> 1) & 3)) << 3);
            glds16(Ain + (size_t)(m0 + row) * HID_ + k0 + j, As + flat);
        }
#pragma unroll
        for (int rr = 0; rr < 2; ++rr) {
            int flat = rr * 1024 + tid * 4;        // float units
            int row = flat >> 5;
            int j = (((tid & 7) ^ (row & 7)) << 2);
            glds16(Wo + (size_t)(n0 + row) * HID_ + k0 + j, Bs + flat);
        }
        __syncthreads();
        bf16x8 af[2], bfr[4];
#pragma unroll
        for (int i = 0; i < 2; ++i) {
            int ra = wave * 32 + i * 16 + l16;
            int pq = (quad ^ ((ra >> 1) & 3)) << 3;   // physical bf16 offset
            af[i] = *reinterpret_cast<const bf16x8*>(&As[ra * 32 + pq]);
        }
#pragma unroll
        for (int i = 0; i < 4; ++i) {
            int rb = i * 16 + l16;
            bfr[i] = frag_cvt_sw(Bs + rb * 32, rb & 7, quad);
        }
#pragma unroll
        for (int mi = 0; mi < 2; ++mi)
#pragma unroll
            for (int ni = 0; ni < 4; ++ni)
                acc[mi][ni] = __builtin_amdgcn_mfma_f32_16x16x32_bf16(af[mi], bfr[ni], acc[mi][ni], 0, 0, 0);
        __syncthreads();
    }
#pragma unroll
    for (int mi = 0; mi < 2; ++mi)
#pragma unroll
        for (int ni = 0; ni < 4; ++ni)
#pragma unroll
            for (int r = 0; r < 4; ++r) {
                int m = m0 + wave * 32 + mi * 16 + quad * 4 + r;
                int n = n0 + ni * 16 + l16;
                out[(size_t)m * HID_ + n] = acc[mi][ni][r];
            }
}

// ---------------------------------------------------------------------------
extern "C" void kernel_launch(void* const* d_in, const int* in_sizes, int n_in,
                              void* d_out, int out_size, void* d_ws, size_t ws_size,
                              hipStream_t stream)
{
    const float* X  = (const float*)d_in[0];
    // d_in[1] = position_ids (broadcast arange(S); pos derived from s index)
    const float* Wq = (const float*)d_in[2];
    const float* Wk = (const float*)d_in[3];
    const float* Wv = (const float*)d_in[4];
    const float* Wo = (const float*)d_in[5];

    char* ws = (char*)d_ws;
    const size_t elems = (size_t)B_ * NH_ * S_ * HD_;   // 4,194,304
    bf16_t* Q  = (bf16_t*)ws;
    bf16_t* K  = Q + elems;
    bf16_t* Vt = K + elems;
    bf16_t* A  = Vt + elems;   // total 33.5 MB

    qkv_gemm<<<dim3(64, 12), 256, 0, stream>>>(X, Wq, Wk, Wv, Q, K, Vt);
    attn_mfma<<<dim3(32, 8, 4), 256, 0, stream>>>(Q, K, Vt, A);
    out_proj<<<dim3(64, 8), 256, 0, stream>>>(A, Wo, (float*)d_out);
}

// Round 11
// 144.964 us; speedup vs baseline: 2.8632x; 1.0639x over previous
//
#include <hip/hip_runtime.h>
#include <hip/hip_bf16.h>
#include <math.h>

// MimiAttention: B=4, S=2048, HID=512, NH=8, HD=64, SW=250, theta=10000
// Round 11: round-6 structure (cvt once -> bf16 staging, no per-k-iter cvt)
// + round-10 XOR swizzle so bf16 frag reads are 2-way (free) instead of
// 8-way. Swizzle: physical 16B slot = logical ^ ((row>>1)&3).
// Kernels: cvt_all -> qkv_gemm(+RoPE,Vt) -> attn_mfma -> out_proj.

#define B_   4
#define S_   2048
#define HID_ 512
#define NH_  8
#define HD_  64
#define SW_  250

typedef __bf16 bf16x8 __attribute__((ext_vector_type(8)));
typedef __bf16 bf16x4 __attribute__((ext_vector_type(4)));
typedef float f32x4 __attribute__((ext_vector_type(4)));
using bf16_t = __hip_bfloat16;
typedef unsigned int u32;

// async global->LDS, 16 B per lane (wave-uniform base + lane*16 semantics)
__device__ __forceinline__ void glds16(const void* g, void* l) {
    __builtin_amdgcn_global_load_lds(
        (const __attribute__((address_space(1))) u32*)g,
        (__attribute__((address_space(3))) u32*)l, 16, 0, 0);
}

// ---------------------------------------------------------------------------
// One fused fp32->bf16 convert pass. 2048 elems/block.
// blocks: [0,2048) X | [2048,2176) Wq | [2176,2304) Wk | [2304,2432) Wv |
//         [2432,2560) Wo
// ---------------------------------------------------------------------------
__global__ __launch_bounds__(256) void cvt_all(
    const float* __restrict__ X,  const float* __restrict__ Wq,
    const float* __restrict__ Wk, const float* __restrict__ Wv,
    const float* __restrict__ Wo,
    bf16_t* __restrict__ Xb, bf16_t* __restrict__ Wcat, bf16_t* __restrict__ Wob)
{
    const int blk = blockIdx.x;
    const float* s; bf16_t* d; size_t base;
    if (blk < 2048)      { s = X;  d = Xb;            base = (size_t)blk * 2048; }
    else if (blk < 2176) { s = Wq; d = Wcat;          base = (size_t)(blk - 2048) * 2048; }
    else if (blk < 2304) { s = Wk; d = Wcat + 262144; base = (size_t)(blk - 2176) * 2048; }
    else if (blk < 2432) { s = Wv; d = Wcat + 524288; base = (size_t)(blk - 2304) * 2048; }
    else                 { s = Wo; d = Wob;           base = (size_t)(blk - 2432) * 2048; }
    size_t i = base + (size_t)threadIdx.x * 8;
    float4 a = *reinterpret_cast<const float4*>(s + i);
    float4 b = *reinterpret_cast<const float4*>(s + i + 4);
    bf16x8 r;
    r[0] = (__bf16)a.x; r[1] = (__bf16)a.y; r[2] = (__bf16)a.z; r[3] = (__bf16)a.w;
    r[4] = (__bf16)b.x; r[5] = (__bf16)b.y; r[6] = (__bf16)b.z; r[7] = (__bf16)b.w;
    *reinterpret_cast<bf16x8*>(d + i) = r;
}

// ---------------------------------------------------------------------------
// Fused QKV GEMM: C[8192x1536] = Xb @ Wcat^T, 128x128 tile, BK=32, bf16
// staging with XOR-swizzled 16B slots (2-way bank access = free).
// Epilogue: RoPE (__sincosf) for Q/K, V stored transposed; 128B-coalesced
// stores via wave-private LDS tile. MFMA layouts (m89/m91).
// ---------------------------------------------------------------------------
__global__ __launch_bounds__(256) void qkv_gemm(
    const bf16_t* __restrict__ Xb, const bf16_t* __restrict__ Wcat,
    bf16_t* __restrict__ Q, bf16_t* __restrict__ Kbuf, bf16_t* __restrict__ Vt)
{
    __shared__ __align__(16) char smem_raw[34816];  // max(16KB stage, 34KB epi)
    bf16_t* As = (bf16_t*)smem_raw;        // 128*32 bf16 = 8 KB
    bf16_t* Bs = As + 4096;                // 128*32 bf16 = 8 KB
    const int tid = threadIdx.x;
    const int wave = tid >> 6, lane = tid & 63;
    const int quad = lane >> 4, l16 = lane & 15;
    const int wm = wave & 1, wn = wave >> 1;
    const int m0 = blockIdx.x * 128, n0 = blockIdx.y * 128;

    f32x4 acc[4][4] = {};
    for (int k0 = 0; k0 < HID_; k0 += 32) {
        // stage: 512 slots (16B) per tile, 2 rounds. physical slot rr*256+tid,
        // row = slot>>2, physical-in-row p = slot&3, logical l = p^((row>>1)&3)
#pragma unroll
        for (int rr = 0; rr < 2; ++rr) {
            int slot = rr * 256 + tid;
            int row = slot >> 2;
            int l = (slot & 3) ^ ((row >> 1) & 3);
            glds16(Xb + (size_t)(m0 + row) * HID_ + k0 + l * 8, As + slot * 8);
            glds16(Wcat + (size_t)(n0 + row) * HID_ + k0 + l * 8, Bs + slot * 8);
        }
        __syncthreads();
        bf16x8 af[4], bfr[4];
#pragma unroll
        for (int i = 0; i < 4; ++i) {
            int ra = wm * 64 + i * 16 + l16;
            int rb = wn * 64 + i * 16 + l16;
            int pa = quad ^ ((ra >> 1) & 3);
            int pb = quad ^ ((rb >> 1) & 3);
            af[i]  = *reinterpret_cast<const bf16x8*>(&As[ra * 32 + pa * 8]);
            bfr[i] = *reinterpret_cast<const bf16x8*>(&Bs[rb * 32 + pb * 8]);
        }
#pragma unroll
        for (int mi = 0; mi < 4; ++mi)
#pragma unroll
            for (int ni = 0; ni < 4; ++ni)
                acc[mi][ni] = __builtin_amdgcn_mfma_f32_16x16x32_bf16(af[mi], bfr[ni], acc[mi][ni], 0, 0, 0);
        __syncthreads();
    }

    // ---- epilogue via wave-private 64x68 bf16 LDS tile ----
    const int seg = n0 >> 9;                      // 0=Q 1=K 2=V
    const int hh = ((n0 & 511) + wn * 64) >> 6;   // head of this wave
    bf16_t* wt = (bf16_t*)smem_raw + wave * 4352;
    const int mbase = m0 + wm * 64;
    const int bb = mbase >> 11;
    const int sbase = mbase & (S_ - 1);           // 64-row tile never crosses batch

    if (seg < 2) {
        const float qs = (seg == 0) ? 0.125f : 1.0f;
        const float c = 0.41524101186f;           // log2(10000)/32
        float inv0 = exp2f(-(float)l16 * c);
        float inv1 = exp2f(-(float)(l16 + 16) * c);
#pragma unroll
        for (int mi = 0; mi < 4; ++mi)
#pragma unroll
            for (int r = 0; r < 4; ++r) {
                int lrow = mi * 16 + quad * 4 + r;
                float sf = (float)(sbase + lrow);
#pragma unroll
                for (int ip = 0; ip < 2; ++ip) {
                    float sn, cs_;
                    __sincosf(sf * (ip ? inv1 : inv0), &sn, &cs_);
                    float x1 = acc[mi][ip][r], x2 = acc[mi][ip + 2][r];
                    wt[lrow * 68 + ip * 16 + l16]      = __float2bfloat16((x1 * cs_ - x2 * sn) * qs);
                    wt[lrow * 68 + ip * 16 + l16 + 32] = __float2bfloat16((x2 * cs_ + x1 * sn) * qs);
                }
            }
        bf16_t* Y = (seg == 0) ? Q : Kbuf;
#pragma unroll
        for (int it = 0; it < 8; ++it) {
            int e = it * 64 + lane;
            int sr = e >> 3, doff = (e & 7) * 8;
            size_t g = ((size_t)(bb * NH_ + hh) * S_ + sbase + sr) * HD_ + doff;
            *reinterpret_cast<bf16x8*>(Y + g) =
                *reinterpret_cast<const bf16x8*>(wt + sr * 68 + doff);
        }
    } else {
        // V: deposit transposed (rows = d, cols = s-local), store along s
#pragma unroll
        for (int mi = 0; mi < 4; ++mi)
#pragma unroll
            for (int ni = 0; ni < 4; ++ni)
#pragma unroll
                for (int r = 0; r < 4; ++r)
                    wt[(ni * 16 + l16) * 68 + mi * 16 + quad * 4 + r] =
                        __float2bfloat16(acc[mi][ni][r]);
#pragma unroll
        for (int it = 0; it < 8; ++it) {
            int e = it * 64 + lane;
            int d = e >> 3, soff = (e & 7) * 8;
            size_t g = ((size_t)(bb * NH_ + hh) * HD_ + d) * S_ + sbase + soff;
            *reinterpret_cast<bf16x8*>(Vt + g) =
                *reinterpret_cast<const bf16x8*>(wt + d * 68 + soff);
        }
    }
}

// ---------------------------------------------------------------------------
// One-pass full-window attention (unchanged; passed rounds 6/8/9/10).
// ---------------------------------------------------------------------------
__global__ __launch_bounds__(256) void attn_mfma(
    const bf16_t* __restrict__ Q, const bf16_t* __restrict__ K,
    const bf16_t* __restrict__ Vt, bf16_t* __restrict__ A)
{
    __shared__ __align__(16) __bf16 pt[4][16][296];
    __shared__ float sums_l[4][16];
    const int wave = threadIdx.x >> 6, lane = threadIdx.x & 63;
    const int quad = lane >> 4, l16 = lane & 15;
    const int h = blockIdx.y, b = blockIdx.z;
    const int q0 = (blockIdx.x * 4 + wave) * 16;
    const size_t bh  = (size_t)(b * NH_ + h) * S_;
    const size_t bhd = (size_t)(b * NH_ + h) * HD_;

    bf16x8 qf0, qf1;
    {
        const bf16_t* qp = Q + (bh + q0 + l16) * HD_ + quad * 8;
        qf0 = *reinterpret_cast<const bf16x8*>(qp);
        qf1 = *reinterpret_cast<const bf16x8*>(qp + 32);
    }
    const int kstart = (q0 > SW_) ? ((q0 - SW_) & ~31) : 0;
    const int nt = (q0 + 15 - kstart + 32) >> 5;   // 1..9, wave-uniform
    const int qq = q0 + l16;

    f32x4 s[9][2];
#pragma unroll
    for (int t = 0; t < 9; ++t) {
        if (t < nt) {
            const int kb = kstart + t * 32;
#pragma unroll
            for (int half = 0; half < 2; ++half) {
                const bf16_t* kp = K + (bh + kb + half * 16 + l16) * HD_ + quad * 8;
                bf16x8 k0 = *reinterpret_cast<const bf16x8*>(kp);
                bf16x8 k1 = *reinterpret_cast<const bf16x8*>(kp + 32);
                f32x4 z = {};
                z = __builtin_amdgcn_mfma_f32_16x16x32_bf16(k0, qf0, z, 0, 0, 0);
                z = __builtin_amdgcn_mfma_f32_16x16x32_bf16(k1, qf1, z, 0, 0, 0);
                const int kbase = kb + half * 16 + quad * 4;
#pragma unroll
                for (int r = 0; r < 4; ++r) {
                    int key = kbase + r;
                    bool keep = (key <= qq) && (qq - key <= SW_);
                    s[t][half][r] = keep ? z[r] : -3.0e38f;
                }
            }
        }
    }
    float mx = -3.0e38f;
#pragma unroll
    for (int t = 0; t < 9; ++t)
        if (t < nt)
#pragma unroll
            for (int half = 0; half < 2; ++half)
#pragma unroll
                for (int r = 0; r < 4; ++r)
                    mx = fmaxf(mx, s[t][half][r]);
    mx = fmaxf(mx, __shfl_xor(mx, 16, 64));
    mx = fmaxf(mx, __shfl_xor(mx, 32, 64));

    float sum = 0.f;
#pragma unroll
    for (int t = 0; t < 9; ++t)
        if (t < nt)
#pragma unroll
            for (int half = 0; half < 2; ++half) {
                bf16x4 pk;
#pragma unroll
                for (int r = 0; r < 4; ++r) {
                    float p = __expf(s[t][half][r] - mx);
                    sum += p;
                    pk[r] = (__bf16)p;
                }
                *reinterpret_cast<bf16x4*>(&pt[wave][l16][t * 32 + half * 16 + quad * 4]) = pk;
            }
    sum += __shfl_xor(sum, 16, 64);
    sum += __shfl_xor(sum, 32, 64);
    if (quad == 0) sums_l[wave][l16] = sum;   // wave-local, no barrier

    f32x4 o[4] = {};
#pragma unroll
    for (int t = 0; t < 9; ++t) {
        if (t < nt) {
            const int kb = kstart + t * 32;
            bf16x8 pf = *reinterpret_cast<const bf16x8*>(&pt[wave][l16][t * 32 + quad * 8]);
#pragma unroll
            for (int nf = 0; nf < 4; ++nf) {
                const bf16_t* vp = Vt + (bhd + nf * 16 + l16) * S_ + kb + quad * 8;
                bf16x8 vf = *reinterpret_cast<const bf16x8*>(vp);
                o[nf] = __builtin_amdgcn_mfma_f32_16x16x32_bf16(pf, vf, o[nf], 0, 0, 0);
            }
        }
    }
    float inv_l[4];
#pragma unroll
    for (int r = 0; r < 4; ++r) inv_l[r] = 1.0f / sums_l[wave][quad * 4 + r];
#pragma unroll
    for (int nf = 0; nf < 4; ++nf)
#pragma unroll
        for (int r = 0; r < 4; ++r) {
            int qr = q0 + quad * 4 + r;
            A[((size_t)(b * S_ + qr)) * HID_ + h * HD_ + nf * 16 + l16] =
                __float2bfloat16(o[nf][r] * inv_l[r]);
        }
}

// ---------------------------------------------------------------------------
// Output projection: out[8192x512] = A @ Wob^T (both bf16), 128x64 tile,
// BK=32, swizzled staging on both tiles, fp32 out.
// ---------------------------------------------------------------------------
__global__ __launch_bounds__(256) void out_proj(
    const bf16_t* __restrict__ Ain, const bf16_t* __restrict__ Wob,
    float* __restrict__ out)
{
    __shared__ __align__(16) bf16_t As[128 * 32];  // 8 KB
    __shared__ __align__(16) bf16_t Bs[64 * 32];   // 4 KB
    const int tid = threadIdx.x;
    const int wave = tid >> 6, lane = tid & 63;
    const int quad = lane >> 4, l16 = lane & 15;
    const int m0 = blockIdx.x * 128, n0 = blockIdx.y * 64;

    f32x4 acc[2][4] = {};
    for (int k0 = 0; k0 < HID_; k0 += 32) {
#pragma unroll
        for (int rr = 0; rr < 2; ++rr) {
            int slot = rr * 256 + tid;
            int row = slot >> 2;
            int l = (slot & 3) ^ ((row >> 1) & 3);
            glds16(Ain + (size_t)(m0 + row) * HID_ + k0 + l * 8, As + slot * 8);
        }
        {
            int slot = tid;                        // 256 slots: one round
            int row = slot >> 2;
            int l = (slot & 3) ^ ((row >> 1) & 3);
            glds16(Wob + (size_t)(n0 + row) * HID_ + k0 + l * 8, Bs + slot * 8);
        }
        __syncthreads();
        bf16x8 af[2], bfr[4];
#pragma unroll
        for (int i = 0; i < 2; ++i) {
            int ra = wave * 32 + i * 16 + l16;
            int pa = quad ^ ((ra >> 1) & 3);
            af[i] = *reinterpret_cast<const bf16x8*>(&As[ra * 32 + pa * 8]);
        }
#pragma unroll
        for (int i = 0; i < 4; ++i) {
            int rb = i * 16 + l16;
            int pb = quad ^ ((rb >> 1) & 3);
            bfr[i] = *reinterpret_cast<const bf16x8*>(&Bs[rb * 32 + pb * 8]);
        }
#pragma unroll
        for (int mi = 0; mi < 2; ++mi)
#pragma unroll
            for (int ni = 0; ni < 4; ++ni)
                acc[mi][ni] = __builtin_amdgcn_mfma_f32_16x16x32_bf16(af[mi], bfr[ni], acc[mi][ni], 0, 0, 0);
        __syncthreads();
    }
#pragma unroll
    for (int mi = 0; mi < 2; ++mi)
#pragma unroll
        for (int ni = 0; ni < 4; ++ni)
#pragma unroll
            for (int r = 0; r < 4; ++r) {
                int m = m0 + wave * 32 + mi * 16 + quad * 4 + r;
                int n = n0 + ni * 16 + l16;
                out[(size_t)m * HID_ + n] = acc[mi][ni][r];
            }
}

// ---------------------------------------------------------------------------
extern "C" void kernel_launch(void* const* d_in, const int* in_sizes, int n_in,
                              void* d_out, int out_size, void* d_ws, size_t ws_size,
                              hipStream_t stream)
{
    const float* X  = (const float*)d_in[0];
    // d_in[1] = position_ids (broadcast arange(S); pos derived from s index)
    const float* Wq = (const float*)d_in[2];
    const float* Wk = (const float*)d_in[3];
    const float* Wv = (const float*)d_in[4];
    const float* Wo = (const float*)d_in[5];

    char* ws = (char*)d_ws;
    const size_t elems = (size_t)B_ * NH_ * S_ * HD_;   // 4,194,304
    const size_t wsz   = (size_t)HID_ * HID_;           // 262,144
    bf16_t* Q    = (bf16_t*)ws;
    bf16_t* K    = Q + elems;
    bf16_t* Vt   = K + elems;
    bf16_t* Xb   = Vt + elems;          // aliased: A overwrites Xb after qkv
    bf16_t* A    = Xb;
    bf16_t* Wcat = Xb + elems;
    bf16_t* Wob  = Wcat + 3 * wsz;      // total ~35.6 MB

    cvt_all<<<2560, 256, 0, stream>>>(X, Wq, Wk, Wv, Wo, Xb, Wcat, Wob);
    qkv_gemm<<<dim3(64, 12), 256, 0, stream>>>(Xb, Wcat, Q, K, Vt);
    attn_mfma<<<dim3(32, 8, 4), 256, 0, stream>>>(Q, K, Vt, A);
    out_proj<<<dim3(64, 8), 256, 0, stream>>>(A, Wob, (float*)d_out);
}